// Round 2
// baseline (224.345 us; speedup 1.0000x reference)
//
#include <hip/hip_runtime.h>

// Problem constants (fixed by the reference)
#define BATCH   128
#define C_IN    3
#define C_OUT   16
#define HW      65536                 // 256*256
#define PLANES  (BATCH * C_IN)        // 384
#define BPP     4                     // blocks per plane (1536 blocks / 256 CUs = 6/CU, balanced)
#define NBLK    (PLANES * BPP)        // 1536
#define F4_PER_PLANE 16384            // HW/4
#define F4_PER_BLOCK (F4_PER_PLANE / BPP)   // 4096
#define THREADS 256

// d_ws layout: [0 .. NBLK-1] float partials, then one uint ticket counter.
#define COUNTER_OFF  NBLK             // in floats

// Single fused kernel: every block reduces a contiguous quarter of one
// (b, ci) plane (float4 coalesced loads, shuffle+LDS tree), writes one
// partial, then the LAST block to finish performs the 3x16 matvec + bias +
// logsumexp for all 128 batch elements. Avoids a dependent 1-block tail
// kernel (saves one graph node + full-device drain latency).
__global__ __launch_bounds__(THREADS) void fused_reduce(
        const float* __restrict__ x,
        const float* __restrict__ weight,   // (C_IN, C_OUT, 3, 3) flat
        const float* __restrict__ bias,     // (C_OUT,)
        float* __restrict__ ws,             // partials + counter
        float* __restrict__ out) {          // (BATCH,)
    // ---- phase 1: partial plane sum ----
    const float4* xp = (const float4*)x + (size_t)blockIdx.x * F4_PER_BLOCK;
    float acc = 0.0f;
#pragma unroll
    for (int i = 0; i < F4_PER_BLOCK / THREADS; ++i) {   // 16 iters, 16 B/lane
        float4 v = xp[i * THREADS + threadIdx.x];
        acc += (v.x + v.y) + (v.z + v.w);
    }
#pragma unroll
    for (int off = 32; off > 0; off >>= 1)
        acc += __shfl_down(acc, off, 64);
    __shared__ float smem[THREADS / 64];
    const int lane = threadIdx.x & 63;
    const int wv   = threadIdx.x >> 6;
    if (lane == 0) smem[wv] = acc;
    __syncthreads();

    __shared__ int is_last;
    if (threadIdx.x == 0) {
        ws[blockIdx.x] = (smem[0] + smem[1]) + (smem[2] + smem[3]);
        __threadfence();                                  // release partial
        unsigned* cnt = (unsigned*)(ws + COUNTER_OFF);
        unsigned prev = atomicAdd(cnt, 1u);               // device-scope
        is_last = (prev == NBLK - 1) ? 1 : 0;
    }
    __syncthreads();
    if (!is_last) return;

    // ---- phase 2: last block finalizes ----
    __threadfence();                                      // acquire partials

    __shared__ float Wsum[C_IN][C_OUT];
    __shared__ float bsh[C_OUT];
    const int t = threadIdx.x;
    if (t < C_IN * C_OUT) {
        float s = 0.0f;
#pragma unroll
        for (int k = 0; k < 9; ++k) s += weight[t * 9 + k];
        Wsum[t / C_OUT][t % C_OUT] = s;
    }
    if (t < C_OUT) bsh[t] = bias[t];
    __syncthreads();

    if (t < BATCH) {
        float S[C_IN];
#pragma unroll
        for (int ci = 0; ci < C_IN; ++ci) {
            float s = 0.0f;
#pragma unroll
            for (int k = 0; k < BPP; ++k)
                s += ws[(t * C_IN + ci) * BPP + k];
            S[ci] = s;
        }
        const float inv_area = 1.0f / (258.0f * 258.0f);
        float m[C_OUT];
        float mmax = -1e30f;
#pragma unroll
        for (int co = 0; co < C_OUT; ++co) {
            float v = (S[0] * Wsum[0][co] + S[1] * Wsum[1][co] + S[2] * Wsum[2][co])
                          * inv_area + bsh[co];
            m[co] = v;
            mmax = fmaxf(mmax, v);
        }
        float se = 0.0f;
#pragma unroll
        for (int co = 0; co < C_OUT; ++co) se += expf(m[co] - mmax);
        out[t] = 10.0f * (logf(se) + mmax);
    }
}

extern "C" void kernel_launch(void* const* d_in, const int* in_sizes, int n_in,
                              void* d_out, int out_size, void* d_ws, size_t ws_size,
                              hipStream_t stream) {
    const float* x      = (const float*)d_in[0];
    const float* weight = (const float*)d_in[1];
    const float* bias   = (const float*)d_in[2];
    float* out = (float*)d_out;
    float* ws  = (float*)d_ws;   // NBLK floats partials + 1 uint counter

    // Zero only the ticket counter (workspace is poisoned 0xAA each call).
    hipMemsetAsync(ws + COUNTER_OFF, 0, sizeof(unsigned), stream);
    fused_reduce<<<NBLK, THREADS, 0, stream>>>(x, weight, bias, ws, out);
}

// Round 3
// 150.917 us; speedup vs baseline: 1.4865x; 1.4865x over previous
//
#include <hip/hip_runtime.h>

// Problem constants (fixed by the reference)
#define BATCH   128
#define C_IN    3
#define C_OUT   16
#define HW      65536                  // 256*256
#define F4_PER_PLANE 16384             // HW/4
#define THREADS 1024                   // 16 waves
#define NWAVES  (THREADS / 64)
#define F4_ITERS (F4_PER_PLANE / THREADS)   // 16 per plane

// One block per batch element: reduce the 3 input planes to per-channel sums
// entirely in-block (no workspace, no atomics, no device fences), then fold
// the 3x16 kernel-sum matvec + bias + logsumexp and write out[b].
__global__ __launch_bounds__(THREADS) void fused_batch(
        const float* __restrict__ x,        // (B, 3, 256, 256)
        const float* __restrict__ weight,   // (C_IN, C_OUT, 3, 3) flat
        const float* __restrict__ bias,     // (C_OUT,)
        float* __restrict__ out) {          // (BATCH,)
    const int b = blockIdx.x;
    const int t = threadIdx.x;
    const float4* xp = (const float4*)x + (size_t)b * (3 * F4_PER_PLANE);

    // ---- per-channel partial sums, coalesced float4 streaming ----
    float a0 = 0.0f, a1 = 0.0f, a2 = 0.0f;
#pragma unroll
    for (int i = 0; i < F4_ITERS; ++i) {
        float4 v0 = xp[0 * F4_PER_PLANE + i * THREADS + t];
        float4 v1 = xp[1 * F4_PER_PLANE + i * THREADS + t];
        float4 v2 = xp[2 * F4_PER_PLANE + i * THREADS + t];
        a0 += (v0.x + v0.y) + (v0.z + v0.w);
        a1 += (v1.x + v1.y) + (v1.z + v1.w);
        a2 += (v2.x + v2.y) + (v2.z + v2.w);
    }

    // ---- wave64 shuffle reduction of the 3 accumulators ----
#pragma unroll
    for (int off = 32; off > 0; off >>= 1) {
        a0 += __shfl_down(a0, off, 64);
        a1 += __shfl_down(a1, off, 64);
        a2 += __shfl_down(a2, off, 64);
    }
    __shared__ float smem[NWAVES][3];
    const int lane = t & 63;
    const int wv   = t >> 6;
    if (lane == 0) { smem[wv][0] = a0; smem[wv][1] = a1; smem[wv][2] = a2; }
    __syncthreads();

    // ---- thread 0: fold kernel sums + bias + logsumexp, write out[b] ----
    if (t == 0) {
        float S[C_IN] = {0.0f, 0.0f, 0.0f};
#pragma unroll
        for (int w = 0; w < NWAVES; ++w) {
            S[0] += smem[w][0];
            S[1] += smem[w][1];
            S[2] += smem[w][2];
        }
        const float inv_area = 1.0f / (258.0f * 258.0f);
        float m[C_OUT];
        float mmax = -1e30f;
#pragma unroll
        for (int co = 0; co < C_OUT; ++co) {
            float v = bias[co];
#pragma unroll
            for (int ci = 0; ci < C_IN; ++ci) {
                float ws9 = 0.0f;
#pragma unroll
                for (int k = 0; k < 9; ++k)
                    ws9 += weight[(ci * C_OUT + co) * 9 + k];
                v += S[ci] * ws9 * inv_area;
            }
            m[co] = v;
            mmax = fmaxf(mmax, v);
        }
        float se = 0.0f;
#pragma unroll
        for (int co = 0; co < C_OUT; ++co) se += expf(m[co] - mmax);
        out[b] = 10.0f * (logf(se) + mmax);
    }
}

extern "C" void kernel_launch(void* const* d_in, const int* in_sizes, int n_in,
                              void* d_out, int out_size, void* d_ws, size_t ws_size,
                              hipStream_t stream) {
    const float* x      = (const float*)d_in[0];
    const float* weight = (const float*)d_in[1];
    const float* bias   = (const float*)d_in[2];
    float* out = (float*)d_out;

    fused_batch<<<BATCH, THREADS, 0, stream>>>(x, weight, bias, out);
}